// Round 6
// baseline (299.991 us; speedup 1.0000x reference)
//
#include <hip/hip_runtime.h>
#include <hip/hip_bf16.h>

#define N_NODES 2048
#define EMB 768
#define NH 8
#define DH 96
#define ALPHA 0.2f
#define SCALE 0.10206207261596575f  // 96^-0.5
#define NGMAX 192
#define WSZ (EMB * EMB)
#define NBLK 512u

typedef __bf16 bf16x8 __attribute__((ext_vector_type(8)));
typedef float f32x4 __attribute__((ext_vector_type(4)));
typedef __attribute__((address_space(3))) unsigned int lds_u32;
typedef __attribute__((address_space(1))) const unsigned int glb_u32;

union pack4 { ushort4 u; __hip_bfloat16 h[4]; };

// ---------------------------------------------------------------- manual grid barrier (device-scope)
// Release: __threadfence (wbL2) before arrive. Acquire: __threadfence (invL1/L2) after target seen.
// Co-residency of all 512 blocks is guaranteed by LDS (72KB -> 2/CU) + launch_bounds(256,2).
// Bounded spin (~50ms) turns a hypothetical deadlock into a wrong answer instead of a hang.
__device__ __forceinline__ void grid_barrier(unsigned* bar, unsigned target)
{
    __syncthreads();
    if (threadIdx.x == 0) {
        __threadfence();
        atomicAdd(bar, 1u);
        int guard = 0;
        while (atomicAdd(bar, 0u) < target && guard < (1 << 22)) {
            __builtin_amdgcn_s_sleep(1);
            guard++;
        }
        __threadfence();
    }
    __syncthreads();
}

// ---------------------------------------------------------------- staging (R4-verified, BK=64 XOR swizzle)
__device__ __forceinline__ void stageA64(
    const __hip_bfloat16* __restrict__ src, int row0, int k0,
    __hip_bfloat16* lds, int wave, int lane)
{
#pragma unroll
    for (int i = 0; i < 4; i++) {                 // 128 rows x 8 chunks
        const int c0 = wave * 256 + i * 64;
        const int c = c0 + lane;
        const int row = c >> 3;
        const int cb = (c & 7) ^ (row & 7);
        const __hip_bfloat16* g = src + (size_t)(row0 + row) * EMB + k0 + cb * 8;
        __builtin_amdgcn_global_load_lds((glb_u32*)g, (lds_u32*)(lds + c0 * 8), 16, 0, 0);
    }
}
__device__ __forceinline__ void stageB64(
    const __hip_bfloat16* __restrict__ src, int row0, int k0,
    __hip_bfloat16* lds, int wave, int lane)
{
#pragma unroll
    for (int i = 0; i < 2; i++) {                 // 64 rows x 8 chunks
        const int c0 = wave * 128 + i * 64;
        const int c = c0 + lane;
        const int row = c >> 3;
        const int cb = (c & 7) ^ (row & 7);
        const __hip_bfloat16* g = src + (size_t)(row0 + row) * EMB + k0 + cb * 8;
        __builtin_amdgcn_global_load_lds((glb_u32*)g, (lds_u32*)(lds + c0 * 8), 16, 0, 0);
    }
}

// ---------------------------------------------------------------- ring-3 counted-vmcnt GEMM phase (R4-verified loop)
// Tile 128(M)x64(N), BK=64, 12 stages, 4 waves (2x2), wave = 64x32 (4x2 frags).
// vmcnt(6) keeps next stage's 6 loads in flight across the barrier; vmcnt(0) only at last stage.
// Ring-3 is required: writes(s+3) are issued only after barrier(s+1), behind all reads of buf(s).
// If avec != null: fused s1/s2 reduction (R2-verified math), 16-lane shfl + atomicAdd.
__device__ __forceinline__ void gemm_phase(
    const __hip_bfloat16* __restrict__ A, const __hip_bfloat16* __restrict__ B,
    float* __restrict__ Cf, int bm, int bn,
    const float* __restrict__ bias1, const float* __restrict__ bias2,
    int accum,
    const float* __restrict__ avec, float* __restrict__ s1, float* __restrict__ s2,
    __hip_bfloat16* smA, __hip_bfloat16* smB, int lane, int wave)
{
    const int wm = wave >> 1, wn = wave & 1;
    const int l15 = lane & 15, quad = lane >> 4;

    f32x4 acc[4][2];
#pragma unroll
    for (int k = 0; k < 4; k++) { acc[k][0] = f32x4{0,0,0,0}; acc[k][1] = f32x4{0,0,0,0}; }

    const int ra0 = wm * 64 + l15;                 // A rows (+0,16,32,48)
    const int rb0 = wn * 32 + l15;                 // B rows (+0,16)
    const int xa = ra0 & 7;
    const int xb = rb0 & 7;

    stageA64(A, bm, 0, smA, wave, lane);
    stageB64(B, bn, 0, smB, wave, lane);

    int bufc = 0;
#pragma unroll 1
    for (int s = 0; s < 12; s++) {
        const int bufn = (bufc == 2) ? 0 : bufc + 1;
        if (s + 1 < 12) {
            const int k0 = (s + 1) * 64;
            stageA64(A, bm, k0, smA + bufn * 8192, wave, lane);
            stageB64(B, bn, k0, smB + bufn * 4096, wave, lane);
            asm volatile("s_waitcnt vmcnt(6)" ::: "memory");   // stage s resident; s+1 in flight
        } else {
            asm volatile("s_waitcnt vmcnt(0)" ::: "memory");
        }
        __builtin_amdgcn_s_barrier();

        const __hip_bfloat16* At = smA + bufc * 8192;
        const __hip_bfloat16* Bt = smB + bufc * 4096;
#pragma unroll
        for (int ks = 0; ks < 2; ks++) {
            const int cq = ks * 4 + quad;
            bf16x8 b0 = *(const bf16x8*)(Bt + (size_t)((rb0     ) * 8 + (cq ^ xb)) * 8);
            bf16x8 b1 = *(const bf16x8*)(Bt + (size_t)((rb0 + 16) * 8 + (cq ^ xb)) * 8);
#pragma unroll
            for (int k = 0; k < 4; k++) {
                bf16x8 av = *(const bf16x8*)(At + (size_t)((ra0 + 16 * k) * 8 + (cq ^ xa)) * 8);
                acc[k][0] = __builtin_amdgcn_mfma_f32_16x16x32_bf16(av, b0, acc[k][0], 0, 0, 0);
                acc[k][1] = __builtin_amdgcn_mfma_f32_16x16x32_bf16(av, b1, acc[k][1], 0, 0, 0);
            }
        }
        bufc = bufn;
    }

    const int col0 = bn + wn * 32 + l15;
    const int col1 = col0 + 16;
    float bv0 = 0.f, bv1 = 0.f;
    if (bias1 != nullptr) {
        bv0 = bias1[col0] + bias2[col0];
        bv1 = bias1[col1] + bias2[col1];
    }
    const int r0 = bm + wm * 64 + quad * 4;
#pragma unroll
    for (int k = 0; k < 4; k++) {
#pragma unroll
        for (int r = 0; r < 4; r++) {
            const int row = r0 + 16 * k + r;
            float* p0 = &Cf[(size_t)row * EMB + col0];
            float* p1 = &Cf[(size_t)row * EMB + col1];
            if (accum) { *p0 += acc[k][0][r]; *p1 += acc[k][1][r]; }
            else       { *p0 = acc[k][0][r] + bv0; *p1 = acc[k][1][r] + bv1; }
        }
    }

    if (avec != nullptr) {
        // wave's 32-col window [cb0,cb0+32) lies in ONE head (96 = 3*32)
        const int cb0 = bn + wn * 32;
        const int h = cb0 / DH;
        const int ch = cb0 % DH + l15;
        const float a10 = avec[ch],      a11 = avec[ch + 16];
        const float a20 = avec[DH + ch], a21 = avec[DH + ch + 16];
#pragma unroll
        for (int k = 0; k < 4; k++) {
#pragma unroll
            for (int r = 0; r < 4; r++) {
                float v1 = acc[k][0][r] * a10 + acc[k][1][r] * a11;
                float v2 = acc[k][0][r] * a20 + acc[k][1][r] * a21;
#pragma unroll
                for (int m = 1; m < 16; m <<= 1) {
                    v1 += __shfl_xor(v1, m);
                    v2 += __shfl_xor(v2, m);
                }
                if (l15 == 0) {
                    const int row = r0 + 16 * k + r;
                    atomicAdd(&s1[row * NH + h], v1);
                    atomicAdd(&s2[row * NH + h], v2);
                }
            }
        }
    }
}

// ---------------------------------------------------------------- mega-kernel: 4 phases, 3 manual grid barriers
// 512 blocks x 256 thr, 72 KB LDS (-> 2 blocks/CU), launch_bounds(256,2) (-> VGPR<=128, 2 blocks/CU feasible).
__global__ __launch_bounds__(256, 2) void mega_kernel(
    const float* __restrict__ eh, const float* __restrict__ er, const float* __restrict__ et,
    const int* __restrict__ h_id, const float* __restrict__ a,
    const float* __restrict__ proj_b, const float* __restrict__ skip_b,
    const float* __restrict__ W_w, const float* __restrict__ proj_w, const float* __restrict__ skip_w,
    __hip_bfloat16* __restrict__ e, __hip_bfloat16* __restrict__ Wb,
    __hip_bfloat16* __restrict__ Pb, __hip_bfloat16* __restrict__ Sb,
    float* __restrict__ Wh, float* __restrict__ s1, float* __restrict__ s2,
    int* __restrict__ cnt, int* __restrict__ lists,
    __hip_bfloat16* __restrict__ at, float* __restrict__ out,
    unsigned* __restrict__ bar)
{
    __shared__ __attribute__((aligned(16))) char lds_raw[73728]; // gemm: 3x16KB A + 3x8KB B

    const int bid = blockIdx.x;
    const int t = threadIdx.x;
    const int lane = t & 63, wave = t >> 6;

    // ================= phase 1: casts + zero s1/s2 + group counting-sort =================
    {
        const float4 z4 = {0.f, 0.f, 0.f, 0.f};
        for (int i = bid * 256 + t; i < 843776; i += 512 * 256) {
            if (i < 393216) {                        // e = concat(eh,er,et) cast
                const int idx = i * 4;
                const int row = idx / EMB, c = idx % EMB;
                const float* src;
                if (c < 256)      src = eh + row * 256 + c;
                else if (c < 512) src = er + row * 256 + (c - 256);
                else              src = et + row * 256 + (c - 512);
                float4 v = *reinterpret_cast<const float4*>(src);
                pack4 p;
                p.h[0] = __float2bfloat16(v.x); p.h[1] = __float2bfloat16(v.y);
                p.h[2] = __float2bfloat16(v.z); p.h[3] = __float2bfloat16(v.w);
                *reinterpret_cast<ushort4*>(e + (size_t)row * EMB + c) = p.u;
            } else if (i < 835584) {                 // three 768x768 weight casts
                const int w = i - 393216;
                const int which = w / 147456;
                const int off = (w % 147456) * 4;
                const float* src = (which == 0 ? W_w : which == 1 ? proj_w : skip_w) + off;
                __hip_bfloat16* dst = (which == 0 ? Wb : which == 1 ? Pb : Sb) + off;
                float4 v = *reinterpret_cast<const float4*>(src);
                pack4 p;
                p.h[0] = __float2bfloat16(v.x); p.h[1] = __float2bfloat16(v.y);
                p.h[2] = __float2bfloat16(v.z); p.h[3] = __float2bfloat16(v.w);
                *reinterpret_cast<ushort4*>(dst) = p.u;
            } else {                                 // zero s1+s2 (contiguous 32768 floats)
                reinterpret_cast<float4*>(s1)[i - 835584] = z4;
            }
        }
        if (bid == 511) {                            // counting sort (R2-verified)
            int* hh = (int*)lds_raw;                 // 2048 ints
            int (*seg)[8] = (int(*)[8])(lds_raw + 8192);
            for (int j = t; j < N_NODES; j += 256) hh[j] = h_id[j];
            __syncthreads();
            const int g = t >> 3, sgt = t & 7;
            int c = 0;
            for (int j = sgt * 256; j < sgt * 256 + 256; j++) c += (hh[j] == g) ? 1 : 0;
            seg[g][sgt] = c;
            __syncthreads();
            int off = 0;
            for (int k = 0; k < sgt; k++) off += seg[g][k];
            int p = off;
            for (int j = sgt * 256; j < sgt * 256 + 256; j++)
                if (hh[j] == g) lists[g * N_NODES + (p++)] = j;
            if (sgt == 7) cnt[g] = off + c;
        }
    }
    grid_barrier(bar, NBLK);

    // ================= phase 2: gemm1 (Wh | skip->out) + fused s1/s2 epilogue =================
    if (bid < 384) {
        const int bnb = bid % 24, bmb = bid / 24;
        const int bm = bmb * 128;
        __hip_bfloat16* smA = (__hip_bfloat16*)lds_raw;
        __hip_bfloat16* smB = (__hip_bfloat16*)(lds_raw + 49152);
        if (bnb < 12) {
            gemm_phase(e, Wb, Wh, bm, bnb * 64, nullptr, nullptr, 0,
                       a, s1, s2, smA, smB, lane, wave);
        } else {
            gemm_phase(e, Sb, out, bm, (bnb - 12) * 64, proj_b, skip_b, 0,
                       nullptr, nullptr, nullptr, smA, smB, lane, wave);
        }
    }
    grid_barrier(bar, 2 * NBLK);

    // ================= phase 3: attention (R4-verified body, LDS overlay) =================
    {
        const int g  = bid & 31;
        const int h  = (bid >> 5) & 7;
        const int dh = bid >> 8;                     // 0/1 -> cols [dh*48, dh*48+48)

        int*   jb  = (int*)lds_raw;                  // 192 ints
        int*   qg  = (int*)(lds_raw + 768);
        float* s2g = (float*)(lds_raw + 1536);
        float (*s1g)[9]  = (float(*)[9])(lds_raw + 2304);   // pad 9: stride-8 would conflict
        float (*Whg)[48] = (float(*)[48])(lds_raw + 9216);

        const int ng = min(cnt[g], NGMAX);
        const int* gl = lists + g * N_NODES;

        for (int j = t; j < ng; j += 256) {
            int node = gl[j];
            jb[j]  = node;
            qg[j]  = node >> 8;
            s2g[j] = s2[node * 8 + h];
            float4 v0 = *reinterpret_cast<const float4*>(s1 + node * 8);
            float4 v1 = *reinterpret_cast<const float4*>(s1 + node * 8 + 4);
            s1g[j][0] = v0.x; s1g[j][1] = v0.y; s1g[j][2] = v0.z; s1g[j][3] = v0.w;
            s1g[j][4] = v1.x; s1g[j][5] = v1.y; s1g[j][6] = v1.z; s1g[j][7] = v1.w;
        }
        __syncthreads();
        for (int idx = t; idx < ng * 12; idx += 256) {
            int jc = idx / 12, dq = idx % 12;
            float4 v = *reinterpret_cast<const float4*>(
                Wh + (size_t)jb[jc] * EMB + h * DH + dh * 48 + dq * 4);
            *reinterpret_cast<float4*>(&Whg[jc][dq * 4]) = v;
        }
        __syncthreads();

        const int half = t >> 7;
        const int d0 = half * 24;
        for (int tr = t & 127; tr < ng; tr += 128) {
            float m = -1e30f;
            for (int j = 0; j < ng; j++) {
                float x = s1g[tr][qg[j]] + s2g[j];
                float ev = (x >= 0.f ? x : ALPHA * x) * SCALE;
                m = fmaxf(m, ev);
            }
            float S = 0.f;
            for (int j = 0; j < ng; j++) {
                float x = s1g[tr][qg[j]] + s2g[j];
                float ev = (x >= 0.f ? x : ALPHA * x) * SCALE;
                S += __expf(ev - m);
            }
            const float ri = 1.f / S;

            float acc[24];
#pragma unroll
            for (int d = 0; d < 24; d++) acc[d] = 0.f;
            for (int j = 0; j < ng; j++) {
                float x = s1g[tr][qg[j]] + s2g[j];
                float ev = (x >= 0.f ? x : ALPHA * x) * SCALE;
                float p = __expf(ev - m) * ri;
#pragma unroll
                for (int d = 0; d < 24; d++) acc[d] += p * Whg[j][d0 + d];
            }
            __hip_bfloat16* po = at + (size_t)jb[tr] * EMB + h * DH + dh * 48 + d0;
#pragma unroll
            for (int d = 0; d < 24; d += 4) {
                pack4 pk;
                pk.h[0] = __float2bfloat16(acc[d]);
                pk.h[1] = __float2bfloat16(acc[d + 1]);
                pk.h[2] = __float2bfloat16(acc[d + 2]);
                pk.h[3] = __float2bfloat16(acc[d + 3]);
                *reinterpret_cast<ushort4*>(po + d) = pk.u;
            }
        }
    }
    grid_barrier(bar, 3 * NBLK);

    // ================= phase 4: gemm2 (out += at @ proj_w^T) =================
    if (bid < 192) {
        const int bnb = bid % 12, bmb = bid / 12;
        __hip_bfloat16* smA = (__hip_bfloat16*)lds_raw;
        __hip_bfloat16* smB = (__hip_bfloat16*)(lds_raw + 49152);
        gemm_phase(at, Pb, out, bmb * 128, bnb * 64, nullptr, nullptr, 1,
                   nullptr, nullptr, nullptr, smA, smB, lane, wave);
    }
}

// ---------------------------------------------------------------- launch
extern "C" void kernel_launch(void* const* d_in, const int* in_sizes, int n_in,
                              void* d_out, int out_size, void* d_ws, size_t ws_size,
                              hipStream_t stream)
{
    const float* eh     = (const float*)d_in[0];
    const float* er     = (const float*)d_in[1];
    const float* et     = (const float*)d_in[2];
    const int*   h_id   = (const int*)d_in[3];
    const float* W_w    = (const float*)d_in[4];
    const float* a      = (const float*)d_in[5];
    const float* proj_w = (const float*)d_in[6];
    const float* proj_b = (const float*)d_in[7];
    const float* skip_w = (const float*)d_in[8];
    const float* skip_b = (const float*)d_in[9];
    float* out = (float*)d_out;   // reference output dtype is f32

    char* ws = (char*)d_ws;
    __hip_bfloat16* e_ws   = (__hip_bfloat16*)(ws);              // 3,145,728 B
    float*          Wh_ws  = (float*)(ws + 3145728);             // 6,291,456 B
    __hip_bfloat16* at_ws  = (__hip_bfloat16*)(ws + 9437184);    // 3,145,728 B
    __hip_bfloat16* Wb_ws  = (__hip_bfloat16*)(ws + 12582912);   // 1,179,648 B
    __hip_bfloat16* Pb_ws  = (__hip_bfloat16*)(ws + 13762560);   // 1,179,648 B
    __hip_bfloat16* Sb_ws  = (__hip_bfloat16*)(ws + 14942208);   // 1,179,648 B
    float*          s1_ws  = (float*)(ws + 16121856);            //    65,536 B (zeroed in phase 1)
    float*          s2_ws  = (float*)(ws + 16187392);            //    65,536 B (contiguous after s1)
    int*            cnt_ws = (int*)(ws + 16252928);              //       128 B
    int*            lst_ws = (int*)(ws + 16253056);              //   262,144 B
    unsigned*       bar_ws = (unsigned*)(ws + 16515200);         //         8 B

    hipMemsetAsync(bar_ws, 0, 8, stream);   // zero barrier counter (stream op, capture-safe)

    mega_kernel<<<512, 256, 0, stream>>>(
        eh, er, et, h_id, a, proj_b, skip_b, W_w, proj_w, skip_w,
        e_ws, Wb_ws, Pb_ws, Sb_ws, Wh_ws, s1_ws, s2_ws,
        cnt_ws, lst_ws, at_ws, out, bar_ws);
}

// Round 7
// 273.731 us; speedup vs baseline: 1.0959x; 1.0959x over previous
//
#include <hip/hip_runtime.h>
#include <hip/hip_bf16.h>

#define N_NODES 2048
#define EMB 768
#define NH 8
#define DH 96
#define ALPHA 0.2f
#define SCALE 0.10206207261596575f  // 96^-0.5
#define NGMAX 192
#define WSZ (EMB * EMB)
#define NBLK 512u

typedef __bf16 bf16x8 __attribute__((ext_vector_type(8)));
typedef float f32x4 __attribute__((ext_vector_type(4)));
typedef __attribute__((address_space(3))) unsigned int lds_u32;
typedef __attribute__((address_space(1))) const unsigned int glb_u32;

union pack4 { ushort4 u; __hip_bfloat16 h[4]; };

// ---------------------------------------------------------------- manual grid barrier v2
// R6's RMW-spin (atomicAdd(bar,0)) serialized ~500 spinners at the coherence point
// (~55us/barrier). v2: arrive = 1 atomic add; wait = agent-scope atomic LOAD spin
// (no RMW serialization) + s_sleep pacing. `wait=false` blocks arrive but don't spin
// (no work in next phase). Fences unchanged from R6 (correctness-proven).
__device__ __forceinline__ void grid_arrive_wait(unsigned* bar, unsigned target, bool wait)
{
    __syncthreads();
    if (threadIdx.x == 0) {
        __threadfence();                                   // release: prior writes visible
        __hip_atomic_fetch_add(bar, 1u, __ATOMIC_RELAXED, __HIP_MEMORY_SCOPE_AGENT);
        if (wait) {
            int guard = 0;
            while (__hip_atomic_load(bar, __ATOMIC_RELAXED, __HIP_MEMORY_SCOPE_AGENT) < target
                   && guard < (1 << 20)) {
                __builtin_amdgcn_s_sleep(2);
                guard++;
            }
            __threadfence();                               // acquire: see others' writes
        }
    }
    __syncthreads();
}

// ---------------------------------------------------------------- staging (R4-verified, BK=64 XOR swizzle)
__device__ __forceinline__ void stageA64(
    const __hip_bfloat16* __restrict__ src, int row0, int k0,
    __hip_bfloat16* lds, int wave, int lane)
{
#pragma unroll
    for (int i = 0; i < 4; i++) {                 // 128 rows x 8 chunks
        const int c0 = wave * 256 + i * 64;
        const int c = c0 + lane;
        const int row = c >> 3;
        const int cb = (c & 7) ^ (row & 7);
        const __hip_bfloat16* g = src + (size_t)(row0 + row) * EMB + k0 + cb * 8;
        __builtin_amdgcn_global_load_lds((glb_u32*)g, (lds_u32*)(lds + c0 * 8), 16, 0, 0);
    }
}
__device__ __forceinline__ void stageB64(
    const __hip_bfloat16* __restrict__ src, int row0, int k0,
    __hip_bfloat16* lds, int wave, int lane)
{
#pragma unroll
    for (int i = 0; i < 2; i++) {                 // 64 rows x 8 chunks
        const int c0 = wave * 128 + i * 64;
        const int c = c0 + lane;
        const int row = c >> 3;
        const int cb = (c & 7) ^ (row & 7);
        const __hip_bfloat16* g = src + (size_t)(row0 + row) * EMB + k0 + cb * 8;
        __builtin_amdgcn_global_load_lds((glb_u32*)g, (lds_u32*)(lds + c0 * 8), 16, 0, 0);
    }
}

// ---------------------------------------------------------------- ring-3 counted-vmcnt GEMM phase (R4-verified loop)
// Tile 128(M)x64(N), BK=64, 12 stages, 4 waves (2x2), wave = 64x32 (4x2 frags).
// vmcnt(6) keeps next stage's 6 loads in flight across the barrier; vmcnt(0) only at last stage.
// If avec != null: fused s1/s2 reduction (R2-verified math), 16-lane shfl + atomicAdd.
__device__ __forceinline__ void gemm_phase(
    const __hip_bfloat16* __restrict__ A, const __hip_bfloat16* __restrict__ B,
    float* __restrict__ Cf, int bm, int bn,
    const float* __restrict__ bias1, const float* __restrict__ bias2,
    int accum,
    const float* __restrict__ avec, float* __restrict__ s1, float* __restrict__ s2,
    __hip_bfloat16* smA, __hip_bfloat16* smB, int lane, int wave)
{
    const int wm = wave >> 1, wn = wave & 1;
    const int l15 = lane & 15, quad = lane >> 4;

    f32x4 acc[4][2];
#pragma unroll
    for (int k = 0; k < 4; k++) { acc[k][0] = f32x4{0,0,0,0}; acc[k][1] = f32x4{0,0,0,0}; }

    const int ra0 = wm * 64 + l15;                 // A rows (+0,16,32,48)
    const int rb0 = wn * 32 + l15;                 // B rows (+0,16)
    const int xa = ra0 & 7;
    const int xb = rb0 & 7;

    stageA64(A, bm, 0, smA, wave, lane);
    stageB64(B, bn, 0, smB, wave, lane);

    int bufc = 0;
#pragma unroll 1
    for (int s = 0; s < 12; s++) {
        const int bufn = (bufc == 2) ? 0 : bufc + 1;
        if (s + 1 < 12) {
            const int k0 = (s + 1) * 64;
            stageA64(A, bm, k0, smA + bufn * 8192, wave, lane);
            stageB64(B, bn, k0, smB + bufn * 4096, wave, lane);
            asm volatile("s_waitcnt vmcnt(6)" ::: "memory");   // stage s resident; s+1 in flight
        } else {
            asm volatile("s_waitcnt vmcnt(0)" ::: "memory");
        }
        __builtin_amdgcn_s_barrier();

        const __hip_bfloat16* At = smA + bufc * 8192;
        const __hip_bfloat16* Bt = smB + bufc * 4096;
#pragma unroll
        for (int ks = 0; ks < 2; ks++) {
            const int cq = ks * 4 + quad;
            bf16x8 b0 = *(const bf16x8*)(Bt + (size_t)((rb0     ) * 8 + (cq ^ xb)) * 8);
            bf16x8 b1 = *(const bf16x8*)(Bt + (size_t)((rb0 + 16) * 8 + (cq ^ xb)) * 8);
#pragma unroll
            for (int k = 0; k < 4; k++) {
                bf16x8 av = *(const bf16x8*)(At + (size_t)((ra0 + 16 * k) * 8 + (cq ^ xa)) * 8);
                acc[k][0] = __builtin_amdgcn_mfma_f32_16x16x32_bf16(av, b0, acc[k][0], 0, 0, 0);
                acc[k][1] = __builtin_amdgcn_mfma_f32_16x16x32_bf16(av, b1, acc[k][1], 0, 0, 0);
            }
        }
        bufc = bufn;
    }

    const int col0 = bn + wn * 32 + l15;
    const int col1 = col0 + 16;
    float bv0 = 0.f, bv1 = 0.f;
    if (bias1 != nullptr) {
        bv0 = bias1[col0] + bias2[col0];
        bv1 = bias1[col1] + bias2[col1];
    }
    const int r0 = bm + wm * 64 + quad * 4;
#pragma unroll
    for (int k = 0; k < 4; k++) {
#pragma unroll
        for (int r = 0; r < 4; r++) {
            const int row = r0 + 16 * k + r;
            float* p0 = &Cf[(size_t)row * EMB + col0];
            float* p1 = &Cf[(size_t)row * EMB + col1];
            if (accum) { *p0 += acc[k][0][r]; *p1 += acc[k][1][r]; }
            else       { *p0 = acc[k][0][r] + bv0; *p1 = acc[k][1][r] + bv1; }
        }
    }

    if (avec != nullptr) {
        // wave's 32-col window [cb0,cb0+32) lies in ONE head (96 = 3*32)
        const int cb0 = bn + wn * 32;
        const int h = cb0 / DH;
        const int ch = cb0 % DH + l15;
        const float a10 = avec[ch],      a11 = avec[ch + 16];
        const float a20 = avec[DH + ch], a21 = avec[DH + ch + 16];
#pragma unroll
        for (int k = 0; k < 4; k++) {
#pragma unroll
            for (int r = 0; r < 4; r++) {
                float v1 = acc[k][0][r] * a10 + acc[k][1][r] * a11;
                float v2 = acc[k][0][r] * a20 + acc[k][1][r] * a21;
#pragma unroll
                for (int m = 1; m < 16; m <<= 1) {
                    v1 += __shfl_xor(v1, m);
                    v2 += __shfl_xor(v2, m);
                }
                if (l15 == 0) {
                    const int row = r0 + 16 * k + r;
                    atomicAdd(&s1[row * NH + h], v1);
                    atomicAdd(&s2[row * NH + h], v2);
                }
            }
        }
    }
}

// ---------------------------------------------------------------- mega-kernel: 4 phases, 3 manual grid barriers
// 512 blocks x 256 thr, 72 KB LDS (-> 2 blocks/CU), launch_bounds(256,2).
__global__ __launch_bounds__(256, 2) void mega_kernel(
    const float* __restrict__ eh, const float* __restrict__ er, const float* __restrict__ et,
    const int* __restrict__ h_id, const float* __restrict__ a,
    const float* __restrict__ proj_b, const float* __restrict__ skip_b,
    const float* __restrict__ W_w, const float* __restrict__ proj_w, const float* __restrict__ skip_w,
    __hip_bfloat16* __restrict__ e, __hip_bfloat16* __restrict__ Wb,
    __hip_bfloat16* __restrict__ Pb, __hip_bfloat16* __restrict__ Sb,
    float* __restrict__ Wh, float* __restrict__ s1, float* __restrict__ s2,
    int* __restrict__ cnt, int* __restrict__ lists,
    __hip_bfloat16* __restrict__ at, float* __restrict__ out,
    unsigned* __restrict__ bar)
{
    __shared__ __attribute__((aligned(16))) char lds_raw[73728]; // gemm: 3x16KB A + 3x8KB B

    const int bid = blockIdx.x;
    const int t = threadIdx.x;
    const int lane = t & 63, wave = t >> 6;

    // ================= phase 1: casts + zero s1/s2 + group counting-sort =================
    {
        const float4 z4 = {0.f, 0.f, 0.f, 0.f};
        for (int i = bid * 256 + t; i < 843776; i += 512 * 256) {
            if (i < 393216) {                        // e = concat(eh,er,et) cast
                const int idx = i * 4;
                const int row = idx / EMB, c = idx % EMB;
                const float* src;
                if (c < 256)      src = eh + row * 256 + c;
                else if (c < 512) src = er + row * 256 + (c - 256);
                else              src = et + row * 256 + (c - 512);
                float4 v = *reinterpret_cast<const float4*>(src);
                pack4 p;
                p.h[0] = __float2bfloat16(v.x); p.h[1] = __float2bfloat16(v.y);
                p.h[2] = __float2bfloat16(v.z); p.h[3] = __float2bfloat16(v.w);
                *reinterpret_cast<ushort4*>(e + (size_t)row * EMB + c) = p.u;
            } else if (i < 835584) {                 // three 768x768 weight casts
                const int w = i - 393216;
                const int which = w / 147456;
                const int off = (w % 147456) * 4;
                const float* src = (which == 0 ? W_w : which == 1 ? proj_w : skip_w) + off;
                __hip_bfloat16* dst = (which == 0 ? Wb : which == 1 ? Pb : Sb) + off;
                float4 v = *reinterpret_cast<const float4*>(src);
                pack4 p;
                p.h[0] = __float2bfloat16(v.x); p.h[1] = __float2bfloat16(v.y);
                p.h[2] = __float2bfloat16(v.z); p.h[3] = __float2bfloat16(v.w);
                *reinterpret_cast<ushort4*>(dst) = p.u;
            } else {                                 // zero s1+s2 (contiguous 32768 floats)
                reinterpret_cast<float4*>(s1)[i - 835584] = z4;
            }
        }
        if (bid == 511) {                            // counting sort (R2-verified)
            int* hh = (int*)lds_raw;                 // 2048 ints
            int (*seg)[8] = (int(*)[8])(lds_raw + 8192);
            for (int j = t; j < N_NODES; j += 256) hh[j] = h_id[j];
            __syncthreads();
            const int g = t >> 3, sgt = t & 7;
            int c = 0;
            for (int j = sgt * 256; j < sgt * 256 + 256; j++) c += (hh[j] == g) ? 1 : 0;
            seg[g][sgt] = c;
            __syncthreads();
            int off = 0;
            for (int k = 0; k < sgt; k++) off += seg[g][k];
            int p = off;
            for (int j = sgt * 256; j < sgt * 256 + 256; j++)
                if (hh[j] == g) lists[g * N_NODES + (p++)] = j;
            if (sgt == 7) cnt[g] = off + c;
        }
    }
    grid_arrive_wait(bar, NBLK, bid < 384);          // only phase-2 workers need to wait

    // ================= phase 2: gemm1 (Wh | skip->out) + fused s1/s2 epilogue =================
    if (bid < 384) {
        const int bnb = bid % 24, bmb = bid / 24;
        const int bm = bmb * 128;
        __hip_bfloat16* smA = (__hip_bfloat16*)lds_raw;
        __hip_bfloat16* smB = (__hip_bfloat16*)(lds_raw + 49152);
        if (bnb < 12) {
            gemm_phase(e, Wb, Wh, bm, bnb * 64, nullptr, nullptr, 0,
                       a, s1, s2, smA, smB, lane, wave);
        } else {
            gemm_phase(e, Sb, out, bm, (bnb - 12) * 64, proj_b, skip_b, 0,
                       nullptr, nullptr, nullptr, smA, smB, lane, wave);
        }
    }
    grid_arrive_wait(bar, 2 * NBLK, true);           // phase 3 uses all blocks

    // ================= phase 3: attention (R4-verified body, LDS overlay) =================
    {
        const int g  = bid & 31;
        const int h  = (bid >> 5) & 7;
        const int dh = bid >> 8;                     // 0/1 -> cols [dh*48, dh*48+48)

        int*   jb  = (int*)lds_raw;                  // 192 ints
        int*   qg  = (int*)(lds_raw + 768);
        float* s2g = (float*)(lds_raw + 1536);
        float (*s1g)[9]  = (float(*)[9])(lds_raw + 2304);   // pad 9: stride-8 would conflict
        float (*Whg)[48] = (float(*)[48])(lds_raw + 9216);

        const int ng = min(cnt[g], NGMAX);
        const int* gl = lists + g * N_NODES;

        for (int j = t; j < ng; j += 256) {
            int node = gl[j];
            jb[j]  = node;
            qg[j]  = node >> 8;
            s2g[j] = s2[node * 8 + h];
            float4 v0 = *reinterpret_cast<const float4*>(s1 + node * 8);
            float4 v1 = *reinterpret_cast<const float4*>(s1 + node * 8 + 4);
            s1g[j][0] = v0.x; s1g[j][1] = v0.y; s1g[j][2] = v0.z; s1g[j][3] = v0.w;
            s1g[j][4] = v1.x; s1g[j][5] = v1.y; s1g[j][6] = v1.z; s1g[j][7] = v1.w;
        }
        __syncthreads();
        for (int idx = t; idx < ng * 12; idx += 256) {
            int jc = idx / 12, dq = idx % 12;
            float4 v = *reinterpret_cast<const float4*>(
                Wh + (size_t)jb[jc] * EMB + h * DH + dh * 48 + dq * 4);
            *reinterpret_cast<float4*>(&Whg[jc][dq * 4]) = v;
        }
        __syncthreads();

        const int half = t >> 7;
        const int d0 = half * 24;
        for (int tr = t & 127; tr < ng; tr += 128) {
            float m = -1e30f;
            for (int j = 0; j < ng; j++) {
                float x = s1g[tr][qg[j]] + s2g[j];
                float ev = (x >= 0.f ? x : ALPHA * x) * SCALE;
                m = fmaxf(m, ev);
            }
            float S = 0.f;
            for (int j = 0; j < ng; j++) {
                float x = s1g[tr][qg[j]] + s2g[j];
                float ev = (x >= 0.f ? x : ALPHA * x) * SCALE;
                S += __expf(ev - m);
            }
            const float ri = 1.f / S;

            float acc[24];
#pragma unroll
            for (int d = 0; d < 24; d++) acc[d] = 0.f;
            for (int j = 0; j < ng; j++) {
                float x = s1g[tr][qg[j]] + s2g[j];
                float ev = (x >= 0.f ? x : ALPHA * x) * SCALE;
                float p = __expf(ev - m) * ri;
#pragma unroll
                for (int d = 0; d < 24; d++) acc[d] += p * Whg[j][d0 + d];
            }
            __hip_bfloat16* po = at + (size_t)jb[tr] * EMB + h * DH + dh * 48 + d0;
#pragma unroll
            for (int d = 0; d < 24; d += 4) {
                pack4 pk;
                pk.h[0] = __float2bfloat16(acc[d]);
                pk.h[1] = __float2bfloat16(acc[d + 1]);
                pk.h[2] = __float2bfloat16(acc[d + 2]);
                pk.h[3] = __float2bfloat16(acc[d + 3]);
                *reinterpret_cast<ushort4*>(po + d) = pk.u;
            }
        }
    }
    grid_arrive_wait(bar, 3 * NBLK, bid < 192);      // only phase-4 workers wait; rest retire

    // ================= phase 4: gemm2 (out += at @ proj_w^T) =================
    if (bid < 192) {
        const int bnb = bid % 12, bmb = bid / 12;
        __hip_bfloat16* smA = (__hip_bfloat16*)lds_raw;
        __hip_bfloat16* smB = (__hip_bfloat16*)(lds_raw + 49152);
        gemm_phase(at, Pb, out, bmb * 128, bnb * 64, nullptr, nullptr, 1,
                   nullptr, nullptr, nullptr, smA, smB, lane, wave);
    }
}

// ---------------------------------------------------------------- launch
extern "C" void kernel_launch(void* const* d_in, const int* in_sizes, int n_in,
                              void* d_out, int out_size, void* d_ws, size_t ws_size,
                              hipStream_t stream)
{
    const float* eh     = (const float*)d_in[0];
    const float* er     = (const float*)d_in[1];
    const float* et     = (const float*)d_in[2];
    const int*   h_id   = (const int*)d_in[3];
    const float* W_w    = (const float*)d_in[4];
    const float* a      = (const float*)d_in[5];
    const float* proj_w = (const float*)d_in[6];
    const float* proj_b = (const float*)d_in[7];
    const float* skip_w = (const float*)d_in[8];
    const float* skip_b = (const float*)d_in[9];
    float* out = (float*)d_out;   // reference output dtype is f32

    char* ws = (char*)d_ws;
    __hip_bfloat16* e_ws   = (__hip_bfloat16*)(ws);              // 3,145,728 B
    float*          Wh_ws  = (float*)(ws + 3145728);             // 6,291,456 B
    __hip_bfloat16* at_ws  = (__hip_bfloat16*)(ws + 9437184);    // 3,145,728 B
    __hip_bfloat16* Wb_ws  = (__hip_bfloat16*)(ws + 12582912);   // 1,179,648 B
    __hip_bfloat16* Pb_ws  = (__hip_bfloat16*)(ws + 13762560);   // 1,179,648 B
    __hip_bfloat16* Sb_ws  = (__hip_bfloat16*)(ws + 14942208);   // 1,179,648 B
    float*          s1_ws  = (float*)(ws + 16121856);            //    65,536 B (zeroed in phase 1)
    float*          s2_ws  = (float*)(ws + 16187392);            //    65,536 B (contiguous after s1)
    int*            cnt_ws = (int*)(ws + 16252928);              //       128 B
    int*            lst_ws = (int*)(ws + 16253056);              //   262,144 B
    unsigned*       bar_ws = (unsigned*)(ws + 16515200);         //         8 B

    hipMemsetAsync(bar_ws, 0, 8, stream);   // zero barrier counter (stream op, capture-safe)

    mega_kernel<<<512, 256, 0, stream>>>(
        eh, er, et, h_id, a, proj_b, skip_b, W_w, proj_w, skip_w,
        e_ws, Wb_ws, Pb_ws, Sb_ws, Wh_ws, s1_ws, s2_ws,
        cnt_ws, lst_ws, at_ws, out, bar_ws);
}

// Round 9
// 163.539 us; speedup vs baseline: 1.8344x; 1.6738x over previous
//
#include <hip/hip_runtime.h>
#include <hip/hip_bf16.h>

#define N_NODES 2048
#define EMB 768
#define NH 8
#define DH 96
#define ALPHA 0.2f
#define SCALE 0.10206207261596575f  // 96^-0.5
#define NGMAX 192
#define WSZ (EMB * EMB)

typedef __bf16 bf16x8 __attribute__((ext_vector_type(8)));
typedef float f32x4 __attribute__((ext_vector_type(4)));
typedef __attribute__((address_space(3))) unsigned int lds_u32;
typedef __attribute__((address_space(1))) const unsigned int glb_u32;

union pack4 { ushort4 u; __hip_bfloat16 h[4]; };

// ---------------------------------------------------------------- prep (R2-verified):
//   b <  1536 : e = concat(eh,er,et) cast to bf16
//   b <  3264 : cast W_w / proj_w / skip_w to bf16
//   b <  3296 : zero s1 + s2 (128 KB contiguous; atomicAdd targets of gemm1 epilogue)
//   b == 3296 : group lists + cnt via 2-phase counting sort (no atomics)
__global__ __launch_bounds__(256) void prep_kernel(
    const float* __restrict__ eh, const float* __restrict__ er, const float* __restrict__ et,
    const float* __restrict__ W0, const float* __restrict__ W1, const float* __restrict__ W2,
    const int* __restrict__ h_id,
    __hip_bfloat16* __restrict__ e, __hip_bfloat16* __restrict__ o0,
    __hip_bfloat16* __restrict__ o1, __hip_bfloat16* __restrict__ o2,
    float4* __restrict__ zbase, int* __restrict__ cnt, int* __restrict__ lists)
{
    const int b = blockIdx.x;
    const int t = threadIdx.x;
    if (b < 3264) {
        const int gtid = b * 256 + t;
        const float* src;
        __hip_bfloat16* dst;
        if (b < 1536) {
            int idx = gtid * 4;
            int i = idx / EMB, c = idx % EMB;
            if (c < 256)      src = eh + i * 256 + c;
            else if (c < 512) src = er + i * 256 + (c - 256);
            else              src = et + i * 256 + (c - 512);
            dst = e + (size_t)i * EMB + c;
        } else {
            int idx = (gtid - 1536 * 256) * 4;
            if (idx < WSZ)          { src = W0 + idx;           dst = o0 + idx; }
            else if (idx < 2 * WSZ) { src = W1 + idx - WSZ;     dst = o1 + idx - WSZ; }
            else                    { src = W2 + idx - 2 * WSZ; dst = o2 + idx - 2 * WSZ; }
        }
        float4 v = *reinterpret_cast<const float4*>(src);
        pack4 p;
        p.h[0] = __float2bfloat16(v.x);
        p.h[1] = __float2bfloat16(v.y);
        p.h[2] = __float2bfloat16(v.z);
        p.h[3] = __float2bfloat16(v.w);
        *reinterpret_cast<ushort4*>(dst) = p.u;
    } else if (b < 3296) {
        const float4 z = {0.f, 0.f, 0.f, 0.f};
        zbase[(size_t)(b - 3264) * 256 + t] = z;       // 32*256 float4 = s1+s2 (128 KB)
    } else {
        // counting sort: 32 groups x 8 segments of 256 nodes (R2/R6/R7-verified)
        __shared__ int hh[N_NODES];
        __shared__ int seg[32][8];
        for (int j = t; j < N_NODES; j += 256) hh[j] = h_id[j];
        __syncthreads();
        const int g = t >> 3, s = t & 7;
        int c = 0;
        for (int j = s * 256; j < s * 256 + 256; j++) c += (hh[j] == g) ? 1 : 0;
        seg[g][s] = c;
        __syncthreads();
        int off = 0;
        for (int k = 0; k < s; k++) off += seg[g][k];
        int p = off;
        for (int j = s * 256; j < s * 256 + 256; j++)
            if (hh[j] == g) lists[g * N_NODES + (p++)] = j;
        if (s == 7) cnt[g] = off + c;
    }
}

// ---------------------------------------------------------------- staging (R4-verified, BK=64 XOR swizzle)
__device__ __forceinline__ void stageA64(
    const __hip_bfloat16* __restrict__ src, int row0, int k0,
    __hip_bfloat16* lds, int wave, int lane)
{
#pragma unroll
    for (int i = 0; i < 4; i++) {                 // 128 rows x 8 chunks
        const int c0 = wave * 256 + i * 64;
        const int c = c0 + lane;
        const int row = c >> 3;
        const int cb = (c & 7) ^ (row & 7);
        const __hip_bfloat16* g = src + (size_t)(row0 + row) * EMB + k0 + cb * 8;
        __builtin_amdgcn_global_load_lds((glb_u32*)g, (lds_u32*)(lds + c0 * 8), 16, 0, 0);
    }
}
__device__ __forceinline__ void stageB64(
    const __hip_bfloat16* __restrict__ src, int row0, int k0,
    __hip_bfloat16* lds, int wave, int lane)
{
#pragma unroll
    for (int i = 0; i < 2; i++) {                 // 64 rows x 8 chunks
        const int c0 = wave * 128 + i * 64;
        const int c = c0 + lane;
        const int row = c >> 3;
        const int cb = (c & 7) ^ (row & 7);
        const __hip_bfloat16* g = src + (size_t)(row0 + row) * EMB + k0 + cb * 8;
        __builtin_amdgcn_global_load_lds((glb_u32*)g, (lds_u32*)(lds + c0 * 8), 16, 0, 0);
    }
}

// ---------------------------------------------------------------- ring-3 counted-vmcnt GEMM (R4/R6/R7-verified)
// Tile 128(M)x64(N), BK=64, 12 stages, 4 waves (2x2), wave = 64x32 (4x2 frags).
// vmcnt(6) keeps next stage's 6 loads in flight across the barrier; vmcnt(0) only at last stage.
// If avec != null: fused s1/s2 reduction (pass-verified in R6/R7 in this exact form).
__device__ __forceinline__ void gemm_phase(
    const __hip_bfloat16* __restrict__ A, const __hip_bfloat16* __restrict__ B,
    float* __restrict__ Cf, int bm, int bn,
    const float* __restrict__ bias1, const float* __restrict__ bias2,
    int accum,
    const float* __restrict__ avec, float* __restrict__ s1, float* __restrict__ s2,
    __hip_bfloat16* smA, __hip_bfloat16* smB, int lane, int wave)
{
    const int wm = wave >> 1, wn = wave & 1;
    const int l15 = lane & 15, quad = lane >> 4;

    f32x4 acc[4][2];
#pragma unroll
    for (int k = 0; k < 4; k++) { acc[k][0] = f32x4{0,0,0,0}; acc[k][1] = f32x4{0,0,0,0}; }

    const int ra0 = wm * 64 + l15;                 // A rows (+0,16,32,48)
    const int rb0 = wn * 32 + l15;                 // B rows (+0,16)
    const int xa = ra0 & 7;
    const int xb = rb0 & 7;

    stageA64(A, bm, 0, smA, wave, lane);
    stageB64(B, bn, 0, smB, wave, lane);

    int bufc = 0;
#pragma unroll 1
    for (int s = 0; s < 12; s++) {
        const int bufn = (bufc == 2) ? 0 : bufc + 1;
        if (s + 1 < 12) {
            const int k0 = (s + 1) * 64;
            stageA64(A, bm, k0, smA + bufn * 8192, wave, lane);
            stageB64(B, bn, k0, smB + bufn * 4096, wave, lane);
            asm volatile("s_waitcnt vmcnt(6)" ::: "memory");   // stage s resident; s+1 in flight
        } else {
            asm volatile("s_waitcnt vmcnt(0)" ::: "memory");
        }
        __builtin_amdgcn_s_barrier();

        const __hip_bfloat16* At = smA + bufc * 8192;
        const __hip_bfloat16* Bt = smB + bufc * 4096;
#pragma unroll
        for (int ks = 0; ks < 2; ks++) {
            const int cq = ks * 4 + quad;
            bf16x8 b0 = *(const bf16x8*)(Bt + (size_t)((rb0     ) * 8 + (cq ^ xb)) * 8);
            bf16x8 b1 = *(const bf16x8*)(Bt + (size_t)((rb0 + 16) * 8 + (cq ^ xb)) * 8);
#pragma unroll
            for (int k = 0; k < 4; k++) {
                bf16x8 av = *(const bf16x8*)(At + (size_t)((ra0 + 16 * k) * 8 + (cq ^ xa)) * 8);
                acc[k][0] = __builtin_amdgcn_mfma_f32_16x16x32_bf16(av, b0, acc[k][0], 0, 0, 0);
                acc[k][1] = __builtin_amdgcn_mfma_f32_16x16x32_bf16(av, b1, acc[k][1], 0, 0, 0);
            }
        }
        bufc = bufn;
    }

    const int col0 = bn + wn * 32 + l15;
    const int col1 = col0 + 16;
    float bv0 = 0.f, bv1 = 0.f;
    if (bias1 != nullptr) {
        bv0 = bias1[col0] + bias2[col0];
        bv1 = bias1[col1] + bias2[col1];
    }
    const int r0 = bm + wm * 64 + quad * 4;
#pragma unroll
    for (int k = 0; k < 4; k++) {
#pragma unroll
        for (int r = 0; r < 4; r++) {
            const int row = r0 + 16 * k + r;
            float* p0 = &Cf[(size_t)row * EMB + col0];
            float* p1 = &Cf[(size_t)row * EMB + col1];
            if (accum) { *p0 += acc[k][0][r]; *p1 += acc[k][1][r]; }   // exclusive-ownership RMW
            else       { *p0 = acc[k][0][r] + bv0; *p1 = acc[k][1][r] + bv1; }
        }
    }

    if (avec != nullptr) {
        // wave's 32-col window [cb0,cb0+32) lies in ONE head (96 = 3*32)
        const int cb0 = bn + wn * 32;
        const int h = cb0 / DH;
        const int ch = cb0 % DH + l15;
        const float a10 = avec[ch],      a11 = avec[ch + 16];
        const float a20 = avec[DH + ch], a21 = avec[DH + ch + 16];
#pragma unroll
        for (int k = 0; k < 4; k++) {
#pragma unroll
            for (int r = 0; r < 4; r++) {
                float v1 = acc[k][0][r] * a10 + acc[k][1][r] * a11;
                float v2 = acc[k][0][r] * a20 + acc[k][1][r] * a21;
#pragma unroll
                for (int m = 1; m < 16; m <<= 1) {
                    v1 += __shfl_xor(v1, m);
                    v2 += __shfl_xor(v2, m);
                }
                if (l15 == 0) {
                    const int row = r0 + 16 * k + r;
                    atomicAdd(&s1[row * NH + h], v1);
                    atomicAdd(&s2[row * NH + h], v2);
                }
            }
        }
    }
}

// standalone wrapper: per block-column select of (B, C, bias, avec)
__global__ __launch_bounds__(256) void gemm_kernel(
    const __hip_bfloat16* __restrict__ A,
    const __hip_bfloat16* __restrict__ B1, const __hip_bfloat16* __restrict__ B2,
    const float* __restrict__ bias1, const float* __restrict__ bias2,
    float* __restrict__ C1, float* __restrict__ C2,
    int nbn1, int accum,
    const float* __restrict__ avec, float* __restrict__ s1, float* __restrict__ s2)
{
    __shared__ __attribute__((aligned(16))) __hip_bfloat16 smA[3][8192]; // 3 x 128x64
    __shared__ __attribute__((aligned(16))) __hip_bfloat16 smB[3][4096]; // 3 x  64x64
    const int t = threadIdx.x;
    const int lane = t & 63, wave = t >> 6;
    const int bnb = blockIdx.x;
    const bool second = bnb >= nbn1;
    if (second) {
        gemm_phase(A, B2, C2, blockIdx.y * 128, (bnb - nbn1) * 64, bias1, bias2, accum,
                   nullptr, nullptr, nullptr, &smA[0][0], &smB[0][0], lane, wave);
    } else {
        gemm_phase(A, B1, C1, blockIdx.y * 128, bnb * 64, nullptr, nullptr, accum,
                   avec, s1, s2, &smA[0][0], &smB[0][0], lane, wave);
    }
}

// ---------------------------------------------------------------- attention (R3-verified, unchanged)
__global__ __launch_bounds__(256) void attn_kernel(
    const float* __restrict__ Wh, const float* __restrict__ s1, const float* __restrict__ s2,
    const int* __restrict__ cnt, const int* __restrict__ lists,
    __hip_bfloat16* __restrict__ out)
{
    const int g  = blockIdx.x & 31;
    const int h  = (blockIdx.x >> 5) & 7;
    const int dh = blockIdx.x >> 8;          // 0/1 -> cols [dh*48, dh*48+48)
    const int t  = threadIdx.x;

    __shared__ int   jb[NGMAX];
    __shared__ int   qg[NGMAX];
    __shared__ float s2g[NGMAX];
    __shared__ float s1g[NGMAX][9];          // pad 9: stride-8 would 16-way conflict
    __shared__ float Whg[NGMAX][48];

    const int ng = min(cnt[g], NGMAX);
    const int* gl = lists + g * N_NODES;

    for (int j = t; j < ng; j += 256) {
        int node = gl[j];
        jb[j]  = node;
        qg[j]  = node >> 8;
        s2g[j] = s2[node * 8 + h];
        float4 v0 = *reinterpret_cast<const float4*>(s1 + node * 8);
        float4 v1 = *reinterpret_cast<const float4*>(s1 + node * 8 + 4);
        s1g[j][0] = v0.x; s1g[j][1] = v0.y; s1g[j][2] = v0.z; s1g[j][3] = v0.w;
        s1g[j][4] = v1.x; s1g[j][5] = v1.y; s1g[j][6] = v1.z; s1g[j][7] = v1.w;
    }
    __syncthreads();
    for (int idx = t; idx < ng * 12; idx += 256) {
        int jc = idx / 12, dq = idx % 12;
        float4 v = *reinterpret_cast<const float4*>(
            Wh + (size_t)jb[jc] * EMB + h * DH + dh * 48 + dq * 4);
        *reinterpret_cast<float4*>(&Whg[jc][dq * 4]) = v;
    }
    __syncthreads();

    const int half = t >> 7;
    const int d0 = half * 24;
    for (int tr = t & 127; tr < ng; tr += 128) {
        float m = -1e30f;
        for (int j = 0; j < ng; j++) {
            float x = s1g[tr][qg[j]] + s2g[j];
            float ev = (x >= 0.f ? x : ALPHA * x) * SCALE;
            m = fmaxf(m, ev);
        }
        float S = 0.f;
        for (int j = 0; j < ng; j++) {
            float x = s1g[tr][qg[j]] + s2g[j];
            float ev = (x >= 0.f ? x : ALPHA * x) * SCALE;
            S += __expf(ev - m);
        }
        const float ri = 1.f / S;

        float acc[24];
#pragma unroll
        for (int d = 0; d < 24; d++) acc[d] = 0.f;
        for (int j = 0; j < ng; j++) {
            float x = s1g[tr][qg[j]] + s2g[j];
            float ev = (x >= 0.f ? x : ALPHA * x) * SCALE;
            float p = __expf(ev - m) * ri;
#pragma unroll
            for (int d = 0; d < 24; d++) acc[d] += p * Whg[j][d0 + d];
        }
        __hip_bfloat16* po = out + (size_t)jb[tr] * EMB + h * DH + dh * 48 + d0;
#pragma unroll
        for (int d = 0; d < 24; d += 4) {
            pack4 pk;
            pk.h[0] = __float2bfloat16(acc[d]);
            pk.h[1] = __float2bfloat16(acc[d + 1]);
            pk.h[2] = __float2bfloat16(acc[d + 2]);
            pk.h[3] = __float2bfloat16(acc[d + 3]);
            *reinterpret_cast<ushort4*>(po + d) = pk.u;
        }
    }
}

// ---------------------------------------------------------------- launch (4 kernels)
extern "C" void kernel_launch(void* const* d_in, const int* in_sizes, int n_in,
                              void* d_out, int out_size, void* d_ws, size_t ws_size,
                              hipStream_t stream)
{
    const float* eh     = (const float*)d_in[0];
    const float* er     = (const float*)d_in[1];
    const float* et     = (const float*)d_in[2];
    const int*   h_id   = (const int*)d_in[3];
    const float* W_w    = (const float*)d_in[4];
    const float* a      = (const float*)d_in[5];
    const float* proj_w = (const float*)d_in[6];
    const float* proj_b = (const float*)d_in[7];
    const float* skip_w = (const float*)d_in[8];
    const float* skip_b = (const float*)d_in[9];
    float* out = (float*)d_out;   // reference output dtype is f32

    char* ws = (char*)d_ws;
    __hip_bfloat16* e_ws   = (__hip_bfloat16*)(ws);              // 3,145,728 B
    float*          Wh_ws  = (float*)(ws + 3145728);             // 6,291,456 B
    __hip_bfloat16* at_ws  = (__hip_bfloat16*)(ws + 9437184);    // 3,145,728 B
    __hip_bfloat16* Wb_ws  = (__hip_bfloat16*)(ws + 12582912);   // 1,179,648 B
    __hip_bfloat16* Pb_ws  = (__hip_bfloat16*)(ws + 13762560);   // 1,179,648 B
    __hip_bfloat16* Sb_ws  = (__hip_bfloat16*)(ws + 14942208);   // 1,179,648 B
    float*          s1_ws  = (float*)(ws + 16121856);            //    65,536 B (zeroed in prep)
    float*          s2_ws  = (float*)(ws + 16187392);            //    65,536 B (contiguous after s1)
    int*            cnt_ws = (int*)(ws + 16252928);              //       128 B
    int*            lst_ws = (int*)(ws + 16253056);              //   262,144 B

    // casts + zero s1/s2 + group lists (counting sort)
    prep_kernel<<<3297, 256, 0, stream>>>(eh, er, et, W_w, proj_w, skip_w, h_id,
                                          e_ws, Wb_ws, Pb_ws, Sb_ws,
                                          (float4*)(ws + 16121856), cnt_ws, lst_ws);

    // gemm1: Wh = e @ W_w^T (+ fused s1/s2) | out = e @ skip_w^T + (proj_b+skip_b)
    gemm_kernel<<<dim3(24, 16), 256, 0, stream>>>(
        e_ws, Wb_ws, Sb_ws, proj_b, skip_b, Wh_ws, out, 12, 0,
        a, s1_ws, s2_ws);

    // attention
    attn_kernel<<<512, 256, 0, stream>>>(Wh_ws, s1_ws, s2_ws, cnt_ws, lst_ws, at_ws);

    // gemm2: out += at @ proj_w^T (exclusive-ownership RMW)
    gemm_kernel<<<dim3(12, 16), 256, 0, stream>>>(
        at_ws, Pb_ws, nullptr, nullptr, nullptr, out, nullptr, 12, 1,
        nullptr, nullptr, nullptr);
}

// Round 10
// 133.962 us; speedup vs baseline: 2.2394x; 1.2208x over previous
//
#include <hip/hip_runtime.h>
#include <hip/hip_bf16.h>

#define N_NODES 2048
#define EMB 768
#define NH 8
#define DH 96
#define ALPHA 0.2f
#define SCALE 0.10206207261596575f  // 96^-0.5
#define NGMAX 192
#define WSZ (EMB * EMB)

typedef __bf16 bf16x8 __attribute__((ext_vector_type(8)));
typedef float f32x4 __attribute__((ext_vector_type(4)));
typedef __attribute__((address_space(3))) unsigned int lds_u32;
typedef __attribute__((address_space(1))) const unsigned int glb_u32;

union pack4 { ushort4 u; __hip_bfloat16 h[4]; };

// ---------------------------------------------------------------- prep: concat-cast e + cast 3 weights + zero cnt
// (R0/R3-verified version, unchanged)
__global__ __launch_bounds__(256) void prep_kernel(
    const float* __restrict__ eh, const float* __restrict__ er, const float* __restrict__ et,
    const float* __restrict__ W0, const float* __restrict__ W1, const float* __restrict__ W2,
    __hip_bfloat16* __restrict__ e, __hip_bfloat16* __restrict__ o0,
    __hip_bfloat16* __restrict__ o1, __hip_bfloat16* __restrict__ o2, int* __restrict__ cnt)
{
    const int b = blockIdx.x;
    const int gtid = b * 256 + threadIdx.x;
    if (gtid < 32) cnt[gtid] = 0;
    const float* src;
    __hip_bfloat16* dst;
    if (b < 1536) {                       // e = concat(eh,er,et)
        int idx = gtid * 4;
        int i = idx / EMB, c = idx % EMB;
        if (c < 256)      src = eh + i * 256 + c;
        else if (c < 512) src = er + i * 256 + (c - 256);
        else              src = et + i * 256 + (c - 512);
        dst = e + (size_t)i * EMB + c;
    } else {                              // three 768x768 weights
        int idx = (gtid - 1536 * 256) * 4;
        if (idx < WSZ)          { src = W0 + idx;           dst = o0 + idx; }
        else if (idx < 2 * WSZ) { src = W1 + idx - WSZ;     dst = o1 + idx - WSZ; }
        else                    { src = W2 + idx - 2 * WSZ; dst = o2 + idx - 2 * WSZ; }
    }
    float4 v = *reinterpret_cast<const float4*>(src);
    pack4 p;
    p.h[0] = __float2bfloat16(v.x);
    p.h[1] = __float2bfloat16(v.y);
    p.h[2] = __float2bfloat16(v.z);
    p.h[3] = __float2bfloat16(v.w);
    *reinterpret_cast<ushort4*>(dst) = p.u;
}

// ---------------------------------------------------------------- BK=128 async-staged MFMA GEMM (R0/R3-proven K-loop)
// Single A-stream, K=768 (6 stages of BK=128). Per block-column select of (B, C, bias):
//   blockIdx.x <  nbn1 : C1 = A@B1^T            (no bias)   [accum: C1 += A@B1^T]
//   blockIdx.x >= nbn1 : C2 = A@B2^T + bias1+bias2
// 64x64 tile/block, 4 waves (2x2), BK=128 double-buffer (64 KB LDS),
// global_load_lds width=16, 16B-chunk XOR swizzle: chunk (row,cb) at row*16+(cb^(row&15)).
// Plain stores / exclusive-ownership RMW — NO atomics.
__device__ __forceinline__ void stage128(
    const __hip_bfloat16* __restrict__ src, int row0, int k0,
    __hip_bfloat16* lds, int wave, int lane)
{
#pragma unroll
    for (int i = 0; i < 4; i++) {
        const int c0 = wave * 256 + i * 64;
        const int c = c0 + lane;
        const int row = c >> 4;
        const int cb = (c & 15) ^ (row & 15);
        const __hip_bfloat16* g = src + (size_t)(row0 + row) * EMB + k0 + cb * 8;
        __builtin_amdgcn_global_load_lds((glb_u32*)g, (lds_u32*)(lds + c0 * 8), 16, 0, 0);
    }
}

__global__ __launch_bounds__(256) void gemm_kernel(
    const __hip_bfloat16* __restrict__ A,
    const __hip_bfloat16* __restrict__ B1, const __hip_bfloat16* __restrict__ B2,
    const float* __restrict__ bias1, const float* __restrict__ bias2,
    float* __restrict__ C1, float* __restrict__ C2,
    int nbn1, int accum)
{
    __shared__ __attribute__((aligned(16))) __hip_bfloat16 sm[2][2][8192]; // [buf][A/B][64x128]

    const int t = threadIdx.x;
    const int lane = t & 63, wave = t >> 6;
    const int wm = wave >> 1, wn = wave & 1;
    const int bnb = blockIdx.x;
    const bool second = bnb >= nbn1;
    const __hip_bfloat16* B = second ? B2 : B1;
    float* Cf = second ? C2 : C1;
    const int bn = (second ? bnb - nbn1 : bnb) * 64;
    const int bm = blockIdx.y * 64;
    const int l15 = lane & 15, quad = lane >> 4;
    const int rA = wm * 32 + l15, rB = wn * 32 + l15;

    f32x4 acc00 = {0.f,0.f,0.f,0.f}, acc01 = {0.f,0.f,0.f,0.f};
    f32x4 acc10 = {0.f,0.f,0.f,0.f}, acc11 = {0.f,0.f,0.f,0.f};

    stage128(A, bm, 0, &sm[0][0][0], wave, lane);
    stage128(B, bn, 0, &sm[0][1][0], wave, lane);

#pragma unroll 1
    for (int s = 0; s < 6; s++) {
        __syncthreads();                  // vmcnt drain: stage s resident
        if (s + 1 < 6) {
            const int k0 = (s + 1) * 128;
            stage128(A, bm, k0, &sm[(s + 1) & 1][0][0], wave, lane);
            stage128(B, bn, k0, &sm[(s + 1) & 1][1][0], wave, lane);
        }
        const __hip_bfloat16* At = &sm[s & 1][0][0];
        const __hip_bfloat16* Bt = &sm[s & 1][1][0];
#pragma unroll
        for (int ks = 0; ks < 4; ks++) {
            const int cq = ks * 4 + quad;
            bf16x8 a0 = *(const bf16x8*)(At + (size_t)(rA * 16        + (cq ^ l15)) * 8);
            bf16x8 a1 = *(const bf16x8*)(At + (size_t)((rA + 16) * 16 + (cq ^ l15)) * 8);
            bf16x8 b0 = *(const bf16x8*)(Bt + (size_t)(rB * 16        + (cq ^ l15)) * 8);
            bf16x8 b1 = *(const bf16x8*)(Bt + (size_t)((rB + 16) * 16 + (cq ^ l15)) * 8);
            acc00 = __builtin_amdgcn_mfma_f32_16x16x32_bf16(a0, b0, acc00, 0, 0, 0);
            acc01 = __builtin_amdgcn_mfma_f32_16x16x32_bf16(a0, b1, acc01, 0, 0, 0);
            acc10 = __builtin_amdgcn_mfma_f32_16x16x32_bf16(a1, b0, acc10, 0, 0, 0);
            acc11 = __builtin_amdgcn_mfma_f32_16x16x32_bf16(a1, b1, acc11, 0, 0, 0);
        }
    }

    const int col0 = bn + wn * 32 + l15;
    const int col1 = col0 + 16;
    float bv0 = 0.f, bv1 = 0.f;
    if (second && bias1 != nullptr) {
        bv0 = bias1[col0] + bias2[col0];
        bv1 = bias1[col1] + bias2[col1];
    }
    const int r0 = bm + wm * 32 + quad * 4;
#pragma unroll
    for (int r = 0; r < 4; r++) {
        const int row0 = r0 + r, row1 = r0 + 16 + r;
        float* p00 = &Cf[(size_t)row0 * EMB + col0];
        float* p01 = &Cf[(size_t)row0 * EMB + col1];
        float* p10 = &Cf[(size_t)row1 * EMB + col0];
        float* p11 = &Cf[(size_t)row1 * EMB + col1];
        if (accum) {       // exclusive ownership: plain load+add+store, no atomics
            *p00 += acc00[r];
            *p01 += acc01[r];
            *p10 += acc10[r];
            *p11 += acc11[r];
        } else {
            *p00 = acc00[r] + bv0;
            *p01 = acc01[r] + bv1;
            *p10 = acc10[r] + bv0;
            *p11 = acc11[r] + bv1;
        }
    }
}

// ---------------------------------------------------------------- s1/s2 + group lists (R0/R3-verified, unchanged)
__global__ __launch_bounds__(256) void s12g_kernel(
    const float* __restrict__ Wh, const float* __restrict__ a,
    float* __restrict__ s1, float* __restrict__ s2,
    const int* __restrict__ h_id, int* __restrict__ cnt, int* __restrict__ lists)
{
    int gid = blockIdx.x * 256 + threadIdx.x;  // [0, N*NH)
    if (gid < N_NODES) {
        int g = h_id[gid];
        int p = atomicAdd(&cnt[g], 1);
        lists[g * N_NODES + p] = gid;
    }
    int i = gid >> 3, h = gid & 7;
    const float* wr = Wh + (size_t)i * EMB + h * DH;
    float acc1 = 0.f, acc2 = 0.f;
    for (int d = 0; d < DH; d++) {
        float w = wr[d];
        acc1 += w * a[d];
        acc2 += w * a[DH + d];
    }
    s1[gid] = acc1;
    s2[gid] = acc2;
}

// ---------------------------------------------------------------- attention: block per (group, head, col-half)
// rows split across 2 thread-halves (t>>7) each owning 24 of the 48 cols -> 2x active lanes in PV.
__global__ __launch_bounds__(256) void attn_kernel(
    const float* __restrict__ Wh, const float* __restrict__ s1, const float* __restrict__ s2,
    const int* __restrict__ cnt, const int* __restrict__ lists,
    __hip_bfloat16* __restrict__ out)
{
    const int g  = blockIdx.x & 31;
    const int h  = (blockIdx.x >> 5) & 7;
    const int dh = blockIdx.x >> 8;          // 0/1 -> cols [dh*48, dh*48+48)
    const int t  = threadIdx.x;

    __shared__ int   jb[NGMAX];
    __shared__ int   qg[NGMAX];
    __shared__ float s2g[NGMAX];
    __shared__ float s1g[NGMAX][9];          // pad 9: stride-8 would 16-way conflict
    __shared__ float Whg[NGMAX][48];

    const int ng = min(cnt[g], NGMAX);
    const int* gl = lists + g * N_NODES;

    for (int j = t; j < ng; j += 256) {
        int node = gl[j];
        jb[j]  = node;
        qg[j]  = node >> 8;
        s2g[j] = s2[node * 8 + h];
        float4 v0 = *reinterpret_cast<const float4*>(s1 + node * 8);
        float4 v1 = *reinterpret_cast<const float4*>(s1 + node * 8 + 4);
        s1g[j][0] = v0.x; s1g[j][1] = v0.y; s1g[j][2] = v0.z; s1g[j][3] = v0.w;
        s1g[j][4] = v1.x; s1g[j][5] = v1.y; s1g[j][6] = v1.z; s1g[j][7] = v1.w;
    }
    __syncthreads();
    for (int idx = t; idx < ng * 12; idx += 256) {
        int jc = idx / 12, dq = idx % 12;
        float4 v = *reinterpret_cast<const float4*>(
            Wh + (size_t)jb[jc] * EMB + h * DH + dh * 48 + dq * 4);
        *reinterpret_cast<float4*>(&Whg[jc][dq * 4]) = v;
    }
    __syncthreads();

    const int half = t >> 7;
    const int d0 = half * 24;
    for (int tr = t & 127; tr < ng; tr += 128) {
        float m = -1e30f;
        for (int j = 0; j < ng; j++) {
            float x = s1g[tr][qg[j]] + s2g[j];
            float ev = (x >= 0.f ? x : ALPHA * x) * SCALE;
            m = fmaxf(m, ev);
        }
        float S = 0.f;
        for (int j = 0; j < ng; j++) {
            float x = s1g[tr][qg[j]] + s2g[j];
            float ev = (x >= 0.f ? x : ALPHA * x) * SCALE;
            S += __expf(ev - m);
        }
        const float ri = 1.f / S;

        float acc[24];
#pragma unroll
        for (int d = 0; d < 24; d++) acc[d] = 0.f;
        for (int j = 0; j < ng; j++) {
            float x = s1g[tr][qg[j]] + s2g[j];
            float ev = (x >= 0.f ? x : ALPHA * x) * SCALE;
            float p = __expf(ev - m) * ri;
#pragma unroll
            for (int d = 0; d < 24; d++) acc[d] += p * Whg[j][d0 + d];
        }
        __hip_bfloat16* po = out + (size_t)jb[tr] * EMB + h * DH + dh * 48 + d0;
#pragma unroll
        for (int d = 0; d < 24; d += 4) {
            pack4 pk;
            pk.h[0] = __float2bfloat16(acc[d]);
            pk.h[1] = __float2bfloat16(acc[d + 1]);
            pk.h[2] = __float2bfloat16(acc[d + 2]);
            pk.h[3] = __float2bfloat16(acc[d + 3]);
            *reinterpret_cast<ushort4*>(po + d) = pk.u;
        }
    }
}

// ---------------------------------------------------------------- launch
extern "C" void kernel_launch(void* const* d_in, const int* in_sizes, int n_in,
                              void* d_out, int out_size, void* d_ws, size_t ws_size,
                              hipStream_t stream)
{
    const float* eh     = (const float*)d_in[0];
    const float* er     = (const float*)d_in[1];
    const float* et     = (const float*)d_in[2];
    const int*   h_id   = (const int*)d_in[3];
    const float* W_w    = (const float*)d_in[4];
    const float* a      = (const float*)d_in[5];
    const float* proj_w = (const float*)d_in[6];
    const float* proj_b = (const float*)d_in[7];
    const float* skip_w = (const float*)d_in[8];
    const float* skip_b = (const float*)d_in[9];
    float* out = (float*)d_out;   // reference output dtype is f32

    char* ws = (char*)d_ws;
    __hip_bfloat16* e_ws   = (__hip_bfloat16*)(ws);              // 3,145,728 B
    float*          Wh_ws  = (float*)(ws + 3145728);             // 6,291,456 B
    __hip_bfloat16* at_ws  = (__hip_bfloat16*)(ws + 9437184);    // 3,145,728 B
    __hip_bfloat16* Wb_ws  = (__hip_bfloat16*)(ws + 12582912);   // 1,179,648 B
    __hip_bfloat16* Pb_ws  = (__hip_bfloat16*)(ws + 13762560);   // 1,179,648 B
    __hip_bfloat16* Sb_ws  = (__hip_bfloat16*)(ws + 14942208);   // 1,179,648 B
    float*          s1_ws  = (float*)(ws + 16121856);            //    65,536 B
    float*          s2_ws  = (float*)(ws + 16187392);            //    65,536 B
    int*            cnt_ws = (int*)(ws + 16252928);              //       128 B
    int*            lst_ws = (int*)(ws + 16253056);              //   262,144 B

    // casts + zero cnt (R0-exact)
    prep_kernel<<<3264, 256, 0, stream>>>(eh, er, et, W_w, proj_w, skip_w,
                                          e_ws, Wb_ws, Pb_ws, Sb_ws, cnt_ws);

    // Fused gemm1: Wh = e @ W_w^T (cols 0..11)  AND  out = e @ skip_w^T + (proj_b+skip_b) (cols 12..23)
    gemm_kernel<<<dim3(24, 32), 256, 0, stream>>>(
        e_ws, Wb_ws, Sb_ws, proj_b, skip_b, Wh_ws, out, 12, 0);

    s12g_kernel<<<64, 256, 0, stream>>>(Wh_ws, a, s1_ws, s2_ws, h_id, cnt_ws, lst_ws);

    attn_kernel<<<512, 256, 0, stream>>>(Wh_ws, s1_ws, s2_ws, cnt_ws, lst_ws, at_ws);

    // gemm2: out += at @ proj_w^T  (single stream, 6 stages, exclusive-ownership RMW)
    gemm_kernel<<<dim3(12, 32), 256, 0, stream>>>(
        at_ws, Pb_ws, nullptr, nullptr, nullptr, out, nullptr, 12, 1);
}